// Round 13
// baseline (818.252 us; speedup 1.0000x reference)
//
#include <hip/hip_runtime.h>
#include <math.h>

#define HID 2048
#define NH 16
#define HD 128
#define INTER 8192
#define BB 2
#define SS 2048
#define MT (BB*SS)

typedef __bf16 bf16x8 __attribute__((ext_vector_type(8)));
typedef _Float16 f16x8 __attribute__((ext_vector_type(8)));
typedef float f32x4 __attribute__((ext_vector_type(4)));
typedef float f32x16 __attribute__((ext_vector_type(16)));
typedef unsigned short u16x8 __attribute__((ext_vector_type(8)));

__device__ __forceinline__ float bf2f(unsigned short u) {
  unsigned v = ((unsigned)u) << 16;
  return __builtin_bit_cast(float, v);
}
__device__ __forceinline__ unsigned short f2bf(float x) {
  unsigned u = __builtin_bit_cast(unsigned, x);
  u += 0x7fffu + ((u >> 16) & 1u);
  return (unsigned short)(u >> 16);
}
__device__ __forceinline__ unsigned short f2h(float x) {
  _Float16 h = (_Float16)x;  // v_cvt_f16_f32, RTN
  return __builtin_bit_cast(unsigned short, h);
}
__device__ __forceinline__ void gll16(const void* g, const void* lds) {
  __builtin_amdgcn_global_load_lds(
      (const __attribute__((address_space(1))) void*)g,
      (__attribute__((address_space(3))) void*)lds, 16, 0, 0);
}
__device__ __forceinline__ int swz(int row) {
  return (row & 7) ^ ((row >> 2) & 4);
}

// ---------------- fused LayerNorm: x1 f16 (for qkv gemm), x2 bf16 ----------
__global__ __launch_bounds__(256) void ln2k(
    const float* __restrict__ X, const float* __restrict__ s1,
    const float* __restrict__ b1, const float* __restrict__ s2,
    const float* __restrict__ b2, unsigned short* __restrict__ X1f,
    unsigned short* __restrict__ X2) {
  const int row = blockIdx.x;
  const int tid = threadIdx.x;
  const float* x = X + (long)row * HID;
  float4 v0 = ((const float4*)x)[tid * 2];
  float4 v1 = ((const float4*)x)[tid * 2 + 1];
  float s = v0.x + v0.y + v0.z + v0.w + v1.x + v1.y + v1.z + v1.w;
  float q = v0.x * v0.x + v0.y * v0.y + v0.z * v0.z + v0.w * v0.w +
            v1.x * v1.x + v1.y * v1.y + v1.z * v1.z + v1.w * v1.w;
#pragma unroll
  for (int off = 1; off < 64; off <<= 1) {
    s += __shfl_xor(s, off);
    q += __shfl_xor(q, off);
  }
  __shared__ float rs[4], rq[4];
  const int wid = tid >> 6, lane = tid & 63;
  if (lane == 0) { rs[wid] = s; rq[wid] = q; }
  __syncthreads();
  s = rs[0] + rs[1] + rs[2] + rs[3];
  q = rq[0] + rq[1] + rq[2] + rq[3];
  const float mu = s * (1.f / HID);
  const float var = q * (1.f / HID) - mu * mu;
  const float rstd = rsqrtf(var + 1e-5f);
  float xv[8] = {v0.x, v0.y, v0.z, v0.w, v1.x, v1.y, v1.z, v1.w};
  u16x8 o1, o2;
#pragma unroll
  for (int e = 0; e < 8; e++) {
    const int j = tid * 8 + e;
    const float xn = (xv[e] - mu) * rstd;
    o1[e] = f2h(xn * s1[j] + b1[j]);
    o2[e] = f2bf(xn * s2[j] + b2[j]);
  }
  *(u16x8*)(X1f + (long)row * HID + tid * 8) = o1;
  *(u16x8*)(X2 + (long)row * HID + tid * 8) = o2;
}

// -- weight transpose: W[k][ldn] cols [coff,coff+N) -> WT[N][K], bf16 or f16
template <bool F16>
__global__ __launch_bounds__(256) void wtrans(const float* __restrict__ W,
                                              unsigned short* __restrict__ WT,
                                              int K, int N, int ldn, int coff) {
  (void)N;
  __shared__ float t[32][33];
  const int n0 = blockIdx.x * 32, k0 = blockIdx.y * 32;
  const int tx = threadIdx.x, ty = threadIdx.y;
#pragma unroll
  for (int r = 0; r < 4; r++)
    t[ty + r * 8][tx] = W[(long)(k0 + ty + r * 8) * ldn + coff + n0 + tx];
  __syncthreads();
#pragma unroll
  for (int r = 0; r < 4; r++) {
    const float v = t[tx][ty + r * 8];
    WT[(long)(n0 + ty + r * 8) * K + k0 + tx] = F16 ? f2h(v) : f2bf(v);
  }
}

// ---------------- rope cos/sin table (f64 angle for accuracy) --------------
__global__ void rope_tab(float2* __restrict__ rope) {
  const int s = blockIdx.x, i = threadIdx.x;  // 2048 x 64
  const double ang = (double)s * pow(10000.0, -(double)i / 64.0);
  rope[s * 64 + i] = make_float2((float)cos(ang), (float)sin(ang));
}

// XCD-chunked bijective block swizzle (grids are all %8==0): each XCD gets a
// contiguous w2 range -> contiguous bn within a bm row -> A-panel L2-resident.
__device__ __forceinline__ int2 xcd_map() {
  const int nwg = gridDim.x * gridDim.y;
  const int flat = blockIdx.y * gridDim.x + blockIdx.x;
  const int w2 = (flat & 7) * (nwg >> 3) + (flat >> 3);
  return make_int2(w2 % gridDim.x, w2 / gridDim.x);  // (bn, bm)
}

// ---- f16 GEMM for all of qkv (128-tile, 32x32x16, dbuf + counted vmcnt) ---
// C[4096][6144] = A[M][K](f16) @ Bt[N][K](f16)^T + bias.
// C/D layout (m74/m101): col=lane&31, row=(reg&3)+8*(reg>>2)+4*(lane>>5).
__global__ __launch_bounds__(256) void gemmqkv(
    const unsigned short* __restrict__ A, const unsigned short* __restrict__ Bt,
    const float* __restrict__ bias, const float2* __restrict__ rope,
    unsigned short* __restrict__ QF, unsigned short* __restrict__ KF,
    unsigned short* __restrict__ Vb) {
  __shared__ unsigned short As[2][128 * 64];
  __shared__ unsigned short Bs[2][128 * 64];
  const int K = HID;
  const int tid = threadIdx.x;
  const int wid = tid >> 6, lane = tid & 63;
  const int l31 = lane & 31, lg = lane >> 5;
  const int wr = wid >> 1, wc = wid & 1;
  const int2 bb = xcd_map();
  const long rA0 = (long)bb.y * 128;
  const long rB0 = (long)bb.x * 128;

  f32x16 acc[2][2] = {};

  auto stage = [&](int kt2, int bu) {
#pragma unroll
    for (int i = 0; i < 4; i++) {
      const int lin = i * 4096 + wid * 1024 + (lane << 4);
      const int row = lin >> 7;
      const int cs = ((lin >> 4) & 7) ^ swz(row);
      const int dst = i * 4096 + wid * 1024;
      gll16(A + (rA0 + row) * (long)K + kt2 * 64 + cs * 8,
            (const char*)As[bu] + dst);
      gll16(Bt + (rB0 + row) * (long)K + kt2 * 64 + cs * 8,
            (const char*)Bs[bu] + dst);
    }
  };

  const int nkt = K / 64;
  stage(0, 0);
  int buf = 0;
  for (int kt = 0; kt < nkt; kt++) {
    if (kt + 1 < nkt) {
      stage(kt + 1, buf ^ 1);  // 8 loads stay in flight across the barrier
      asm volatile("s_waitcnt vmcnt(8)" ::: "memory");  // tile kt landed
    } else {
      asm volatile("s_waitcnt vmcnt(0)" ::: "memory");
    }
    __builtin_amdgcn_s_barrier();
#pragma unroll
    for (int kk = 0; kk < 4; kk++) {
      f16x8 av[2], bv[2];
#pragma unroll
      for (int t = 0; t < 2; t++) {
        const int rowA = wr * 64 + t * 32 + l31;
        const int cha = (kk * 2 + lg) ^ swz(rowA);
        av[t] = *(const f16x8*)((const char*)As[buf] + rowA * 128 + cha * 16);
        const int rowB = wc * 64 + t * 32 + l31;
        const int chb = (kk * 2 + lg) ^ swz(rowB);
        bv[t] = *(const f16x8*)((const char*)Bs[buf] + rowB * 128 + chb * 16);
      }
      __builtin_amdgcn_s_setprio(1);
#pragma unroll
      for (int mt = 0; mt < 2; mt++)
#pragma unroll
        for (int nt = 0; nt < 2; nt++)
          acc[mt][nt] = __builtin_amdgcn_mfma_f32_32x32x16_f16(
              av[mt], bv[nt], acc[mt][nt], 0, 0, 0);
      __builtin_amdgcn_s_setprio(0);
    }
    __builtin_amdgcn_s_barrier();  // all waves done with buf before restage
    buf ^= 1;
  }

  const int b_ = (int)(rA0 >> 11);
#pragma unroll
  for (int mt = 0; mt < 2; mt++) {
#pragma unroll
    for (int nt = 0; nt < 2; nt++) {
      const int col = (int)rB0 + wc * 64 + nt * 32 + l31;
      const float bsv = bias[col];
      const int cq = col & 2047;
      const int i = (cq & 127) >> 1;
      const int hh = (cq >> 7) & 15;
      const int d = cq & 127;
#pragma unroll
      for (int reg = 0; reg < 16; reg++) {
        const int row = (int)rA0 + wr * 64 + mt * 32 + (reg & 3) +
                        8 * (reg >> 2) + 4 * lg;
        const int srow = row & 2047;
        const float v = acc[mt][nt][reg] + bsv;
        if (col < 4096) {
          const float p = __shfl_xor(v, 1);
          const float2 cs = rope[srow * 64 + i];
          const float o = ((lane & 1) == 0) ? (v * cs.x - p * cs.y)
                                            : (p * cs.y + v * cs.x);
          unsigned short* dst = (col < 2048) ? QF : KF;
          dst[((long)(b_ * NH + hh) * SS + srow) * HD + d] = f2h(o);
        } else {
          Vb[(long)row * HID + (col - 4096)] = f2bf(v);
        }
      }
    }
  }
}

// ---------------- V transpose: Vbf [m][2048] -> VT [bh][128][s] ------------
__global__ __launch_bounds__(256) void vtrans(
    const unsigned short* __restrict__ Vb, unsigned short* __restrict__ VTb) {
  __shared__ unsigned short t[32][33];
  const int bh = blockIdx.z, b = bh >> 4, h = bh & 15;
  const int d0 = blockIdx.x * 32, s0 = blockIdx.y * 32;
  const int tx = threadIdx.x, ty = threadIdx.y;
#pragma unroll
  for (int r = 0; r < 4; r++) {
    const int s = s0 + ty + r * 8;
    t[ty + r * 8][tx] = Vb[((long)(b * SS + s)) * HID + h * HD + d0 + tx];
  }
  __syncthreads();
#pragma unroll
  for (int r = 0; r < 4; r++) {
    const int d = d0 + ty + r * 8;
    VTb[((long)bh * HD + d) * SS + s0 + tx] = t[tx][ty + r * 8];
  }
}

// --- 128x128-tile bf16 GEMM, 32x32x16, dbuf + counted vmcnt + XCD swizzle --
// MODE 0: bf16 out; 1: gelu+bf16; 2: +residF(f32)+residB(bf16), f32 out.
template <int MODE>
__global__ __launch_bounds__(256) void gemm128(
    const unsigned short* __restrict__ A, const unsigned short* __restrict__ Bt,
    const float* __restrict__ bias, void* __restrict__ Cout, int M, int N,
    int K, const float* __restrict__ residF,
    const unsigned short* __restrict__ residB) {
  (void)M;
  __shared__ unsigned short As[2][128 * 64];
  __shared__ unsigned short Bs[2][128 * 64];
  const int tid = threadIdx.x;
  const int wid = tid >> 6, lane = tid & 63;
  const int l31 = lane & 31, lg = lane >> 5;
  const int wr = wid >> 1, wc = wid & 1;
  const int2 bb = xcd_map();
  const long rA0 = (long)bb.y * 128;
  const long rB0 = (long)bb.x * 128;

  f32x16 acc[2][2] = {};

  auto stage = [&](int kt2, int bu) {
#pragma unroll
    for (int i = 0; i < 4; i++) {
      const int lin = i * 4096 + wid * 1024 + (lane << 4);
      const int row = lin >> 7;
      const int cs = ((lin >> 4) & 7) ^ swz(row);
      const int dst = i * 4096 + wid * 1024;
      gll16(A + (rA0 + row) * (long)K + kt2 * 64 + cs * 8,
            (const char*)As[bu] + dst);
      gll16(Bt + (rB0 + row) * (long)K + kt2 * 64 + cs * 8,
            (const char*)Bs[bu] + dst);
    }
  };

  const int nkt = K / 64;
  stage(0, 0);
  int buf = 0;
  for (int kt = 0; kt < nkt; kt++) {
    if (kt + 1 < nkt) {
      stage(kt + 1, buf ^ 1);  // 8 loads stay in flight across the barrier
      asm volatile("s_waitcnt vmcnt(8)" ::: "memory");  // tile kt landed
    } else {
      asm volatile("s_waitcnt vmcnt(0)" ::: "memory");
    }
    __builtin_amdgcn_s_barrier();
#pragma unroll
    for (int kk = 0; kk < 4; kk++) {
      bf16x8 av[2], bv[2];
#pragma unroll
      for (int t = 0; t < 2; t++) {
        const int rowA = wr * 64 + t * 32 + l31;
        const int cha = (kk * 2 + lg) ^ swz(rowA);
        av[t] = *(const bf16x8*)((const char*)As[buf] + rowA * 128 + cha * 16);
        const int rowB = wc * 64 + t * 32 + l31;
        const int chb = (kk * 2 + lg) ^ swz(rowB);
        bv[t] = *(const bf16x8*)((const char*)Bs[buf] + rowB * 128 + chb * 16);
      }
      __builtin_amdgcn_s_setprio(1);
#pragma unroll
      for (int mt = 0; mt < 2; mt++)
#pragma unroll
        for (int nt = 0; nt < 2; nt++)
          acc[mt][nt] = __builtin_amdgcn_mfma_f32_32x32x16_bf16(
              av[mt], bv[nt], acc[mt][nt], 0, 0, 0);
      __builtin_amdgcn_s_setprio(0);
    }
    __builtin_amdgcn_s_barrier();  // all waves done with buf before restage
    buf ^= 1;
  }

#pragma unroll
  for (int mt = 0; mt < 2; mt++) {
#pragma unroll
    for (int nt = 0; nt < 2; nt++) {
      const long col = rB0 + wc * 64 + nt * 32 + l31;
      const float bsv = bias[col];
#pragma unroll
      for (int reg = 0; reg < 16; reg++) {
        const long row = rA0 + wr * 64 + mt * 32 + (reg & 3) +
                         8 * (reg >> 2) + 4 * lg;
        float v = acc[mt][nt][reg] + bsv;
        if (MODE == 1) v = 0.5f * v * (1.f + erff(v * 0.7071067811865475f));
        if (MODE == 2) {
          v += residF[row * N + col] + bf2f(residB[row * N + col]);
          ((float*)Cout)[row * N + col] = v;
        } else {
          ((unsigned short*)Cout)[row * N + col] = f2bf(v);
        }
      }
    }
  }
}

// -- flash v5: 8 waves, KVBLK=64, dynamic big-first, dbuf + counted vmcnt ---
// QF/KF: [bh][s][128] f16; VT: [bh][128][s] bf16; AO: [b][s][h*128+d] bf16
__global__ __launch_bounds__(512, 2) void flash(
    const unsigned short* __restrict__ QF, const unsigned short* __restrict__ KF,
    const unsigned short* __restrict__ VT, const float* __restrict__ amask,
    unsigned short* __restrict__ AO) {
  __shared__ unsigned short Kt[2][64 * 128];  // 32KB [key][d] f16, dbuf
  __shared__ unsigned short Vt[2][128 * 64];  // 32KB [d][key] bf16, dbuf
  __shared__ unsigned short Pl[8 * 1024];     // 16KB per-wave 16x64 P bf16
  __shared__ float maskL[SS];                 //  8KB amask*log2e => 88KB total
  // big-first (LPT) dispatch: all qt=15 blocks first, then 14, ...
  const int z = blockIdx.x;
  const int qt = 15 - (z >> 5);
  const int bh = z & 31;
  const int b = bh >> 4, h = bh & 15;
  const int tid = threadIdx.x, wid = tid >> 6, lane = tid & 63;
  const int l16 = lane & 15, lhi = lane >> 4;
  const unsigned short* Qfb = QF + (long)bh * SS * HD;
  const unsigned short* Kfb = KF + (long)bh * SS * HD;
  const unsigned short* Vb = VT + (long)bh * HD * SS;
  const int q0 = qt * 128 + wid * 16;  // 16 q-rows per wave
  const float LOG2E = 1.4426950408889634f;
  const float SCL2 = 16.322232154552f;  // sqrt(128)*log2e

  {  // amask row -> LDS (prescaled); K-loop stays free of global loads
    float4 m0 = ((const float4*)(amask + (long)b * SS))[tid];
    m0.x *= LOG2E; m0.y *= LOG2E; m0.z *= LOG2E; m0.w *= LOG2E;
    ((float4*)maskL)[tid] = m0;
  }

  f16x8 qf[4];
#pragma unroll
  for (int ks = 0; ks < 4; ks++)
    qf[ks] = *(const f16x8*)(Qfb + (long)(q0 + l16) * HD + ks * 32 + lhi * 8);

  // stage tile kt2 (64 keys): 4 loads/thread x 512 thr = 32KB
  auto stage = [&](int kt2, int bu) {
#pragma unroll
    for (int i = 0; i < 2; i++) {
      const int lin = i * 8192 + wid * 1024 + (lane << 4);
      const int dst = i * 8192 + wid * 1024;
      {
        const int row = lin >> 8;  // K rows are 256B (128 f16)
        const int cs = ((lin >> 4) & 15) ^ (row & 7);
        gll16(Kfb + (long)(kt2 * 64 + row) * HD + cs * 8,
              (const char*)Kt[bu] + dst);
      }
      {
        const int row = lin >> 7;  // V rows are 128B (64 bf16 keys)
        const int cs = ((lin >> 4) & 7) ^ (row & 7);
        gll16(Vb + (long)row * SS + kt2 * 64 + cs * 8, (const char*)Vt[bu] + dst);
      }
    }
  };

  f32x4 accO[8] = {};
  float mrow[4], lrow[4];
#pragma unroll
  for (int r = 0; r < 4; r++) { mrow[r] = -3e38f; lrow[r] = 0.f; }

  const int nkt = 2 * qt + 2;
  stage(0, 0);
  asm volatile("s_waitcnt lgkmcnt(0)" ::: "memory");  // maskL writes done
  int buf = 0;
  for (int kt = 0; kt < nkt; kt++) {
    if (kt + 1 < nkt) {
      stage(kt + 1, buf ^ 1);  // 4 loads stay in flight across the barrier
      asm volatile("s_waitcnt vmcnt(4)" ::: "memory");  // tile kt landed
    } else {
      asm volatile("s_waitcnt vmcnt(0)" ::: "memory");
    }
    __builtin_amdgcn_s_barrier();  // raw barrier: no vmcnt(0) drain

    // wave-uniform causal skip (all this wave's rows above the key range)
    const bool active = (kt * 64 <= q0 + 15);
    if (active) {
      // S = Q K^T (f16, 16 MFMAs)
      f32x4 accS[4] = {};
      __builtin_amdgcn_s_setprio(1);
#pragma unroll
      for (int ks = 0; ks < 4; ks++) {
        f16x8 bk[4];
#pragma unroll
        for (int nf = 0; nf < 4; nf++) {
          const int row = nf * 16 + l16;
          const int ch = (ks * 4 + lhi) ^ (row & 7);
          bk[nf] = *(const f16x8*)((const char*)Kt[buf] + row * 256 + ch * 16);
        }
#pragma unroll
        for (int nf = 0; nf < 4; nf++)
          accS[nf] = __builtin_amdgcn_mfma_f32_16x16x32_f16(qf[ks], bk[nf],
                                                            accS[nf], 0, 0, 0);
      }
      __builtin_amdgcn_s_setprio(0);

      // scale to log2 domain + mask + causal
      float mk[4];
#pragma unroll
      for (int nf = 0; nf < 4; nf++) mk[nf] = maskL[kt * 64 + nf * 16 + l16];
#pragma unroll
      for (int nf = 0; nf < 4; nf++)
#pragma unroll
        for (int r = 0; r < 4; r++) {
          const int key = kt * 64 + nf * 16 + l16;
          const int qg = q0 + lhi * 4 + r;
          const float sv = accS[nf][r] * SCL2 + mk[nf];
          accS[nf][r] = (key > qg) ? -1e30f : sv;
        }

      // row maxes over the 16-lane group
      float mx[4];
#pragma unroll
      for (int r = 0; r < 4; r++) {
        float m0 = fmaxf(fmaxf(accS[0][r], accS[1][r]),
                         fmaxf(accS[2][r], accS[3][r]));
        m0 = fmaxf(m0, __shfl_xor(m0, 1));
        m0 = fmaxf(m0, __shfl_xor(m0, 2));
        m0 = fmaxf(m0, __shfl_xor(m0, 4));
        m0 = fmaxf(m0, __shfl_xor(m0, 8));
        mx[r] = m0;
      }
      // defer-rescale (THR=8 in log2 domain)
      bool defer = true;
#pragma unroll
      for (int r = 0; r < 4; r++) defer = defer && (mx[r] <= mrow[r] + 8.f);
      if (!__all(defer)) {
#pragma unroll
        for (int r = 0; r < 4; r++) {
          const float mnew = fmaxf(mrow[r], mx[r]);
          const float alpha = exp2f(mrow[r] - mnew);
          mrow[r] = mnew;
          lrow[r] *= alpha;
#pragma unroll
          for (int nf2 = 0; nf2 < 8; nf2++) accO[nf2][r] *= alpha;
        }
      }
      // P = exp2(S - m) -> per-wave LDS (16x64 bf16, 128B rows, swizzled)
#pragma unroll
      for (int r = 0; r < 4; r++) {
        const int rowl = lhi * 4 + r;
        const int qg = q0 + rowl;
        float rsum = 0.f;
#pragma unroll
        for (int nf = 0; nf < 4; nf++) {
          const int key = kt * 64 + nf * 16 + l16;
          const float p = (key > qg) ? 0.f : exp2f(accS[nf][r] - mrow[r]);
          rsum += p;
          const int colv = nf * 16 + l16;
          const int slot = (colv >> 3) ^ (rowl & 7);
          *(unsigned short*)((char*)Pl + wid * 2048 + rowl * 128 + slot * 16 +
                             (colv & 7) * 2) = f2bf(p);
        }
        rsum += __shfl_xor(rsum, 1);
        rsum += __shfl_xor(rsum, 2);
        rsum += __shfl_xor(rsum, 4);
        rsum += __shfl_xor(rsum, 8);
        lrow[r] += rsum;
      }

      // O += P V  (16 MFMAs, bf16)
      __builtin_amdgcn_s_setprio(1);
#pragma unroll
      for (int ks2 = 0; ks2 < 2; ks2++) {
        const int chp = (ks2 * 4 + lhi) ^ (l16 & 7);
        bf16x8 pa =
            *(const bf16x8*)((const char*)Pl + wid * 2048 + l16 * 128 + chp * 16);
#pragma unroll
        for (int nf2 = 0; nf2 < 8; nf2++) {
          const int rowv = nf2 * 16 + l16;
          const int ch = (ks2 * 4 + lhi) ^ (rowv & 7);
          bf16x8 vv =
              *(const bf16x8*)((const char*)Vt[buf] + rowv * 128 + ch * 16);
          accO[nf2] = __builtin_amdgcn_mfma_f32_16x16x32_bf16(pa, vv,
                                                              accO[nf2], 0, 0, 0);
        }
      }
      __builtin_amdgcn_s_setprio(0);
    }  // active
    __builtin_amdgcn_s_barrier();  // all waves done with buf before restage
    buf ^= 1;
  }

#pragma unroll
  for (int nf2 = 0; nf2 < 8; nf2++)
#pragma unroll
    for (int r = 0; r < 4; r++) {
      const int qg = q0 + lhi * 4 + r;
      const int d = nf2 * 16 + l16;
      const float v = accO[nf2][r] / lrow[r];
      AO[((long)(b * SS + qg)) * HID + h * HD + d] = f2bf(v);
    }
}

extern "C" void kernel_launch(void* const* d_in, const int* in_sizes, int n_in,
                              void* d_out, int out_size, void* d_ws,
                              size_t ws_size, hipStream_t stream) {
  (void)in_sizes; (void)n_in; (void)out_size;
  const float* hidden = (const float*)d_in[0];
  const float* amask = (const float*)d_in[1];
  const float* w_qkv = (const float*)d_in[2];
  const float* b_qkv = (const float*)d_in[3];
  const float* w_o = (const float*)d_in[4];
  const float* b_o = (const float*)d_in[5];
  const float* ln1s = (const float*)d_in[6];
  const float* ln1b = (const float*)d_in[7];
  const float* ln2s = (const float*)d_in[8];
  const float* ln2b = (const float*)d_in[9];
  const float* w_in = (const float*)d_in[10];
  const float* b_in = (const float*)d_in[11];
  const float* w_out = (const float*)d_in[12];
  const float* b_out = (const float*)d_in[13];

  char* ws = (char*)d_ws;
  // liveness-aliased workspace (<=178MB; >=209MB verified available)
  unsigned short* X1f = (unsigned short*)(ws + 0);           // 16MB f16, later AO
  unsigned short* X2  = (unsigned short*)(ws + 16777216);    // 16MB bf16
  unsigned short* Vbf = (unsigned short*)(ws + 33554432);    // 16MB bf16
  unsigned short* WQ  = (unsigned short*)(ws + 50331648);    // 24MB f16 [6144][2048]
  unsigned short* QFb = (unsigned short*)(ws + 75497472);    // 16MB f16
  unsigned short* KFb = (unsigned short*)(ws + 92274688);    // 16MB f16
  unsigned short* VTb = (unsigned short*)(ws + 109051904);   // 16MB bf16
  unsigned short* ATT = (unsigned short*)(ws + 125829120);   // 16MB bf16
  unsigned short* WD  = (unsigned short*)(ws + 142606336);   // 32MB bf16 (Wo/Win/Wout)
  float2* ROPE = (float2*)(ws + 176160768);                  // 1MB
  if (ws_size < 177209344) return;

  unsigned short* AO = X1f;  // x1 dead after gemmqkv
  unsigned short* H1 = WQ;   // WQ+QFb+KFb dead after flash: 64MB region

  ln2k<<<MT, 256, 0, stream>>>(hidden, ln1s, ln1b, ln2s, ln2b, X1f, X2);
  rope_tab<<<SS, 64, 0, stream>>>(ROPE);
  // qkv: one f16 GEMM (32x32 MFMA, dbuf pipeline), rope fused for q,k
  wtrans<true><<<dim3(192, 64), dim3(32, 8), 0, stream>>>(w_qkv, WQ, HID,
                                                          3 * HID, 3 * HID, 0);
  gemmqkv<<<dim3(48, 32), 256, 0, stream>>>(X1f, WQ, b_qkv, ROPE, QFb, KFb,
                                            Vbf);
  vtrans<<<dim3(4, 64, 32), dim3(32, 8), 0, stream>>>(Vbf, VTb);
  flash<<<512, 512, 0, stream>>>(QFb, KFb, VTb, amask, AO);
  // attention projection
  wtrans<false><<<dim3(64, 64), dim3(32, 8), 0, stream>>>(w_o, WD, HID, HID,
                                                          HID, 0);
  gemm128<0><<<dim3(16, 32), 256, 0, stream>>>(AO, WD, b_o, ATT, MT, HID, HID,
                                               nullptr, nullptr);
  // mlp
  wtrans<false><<<dim3(256, 64), dim3(32, 8), 0, stream>>>(w_in, WD, HID,
                                                           INTER, INTER, 0);
  gemm128<1><<<dim3(64, 32), 256, 0, stream>>>(X2, WD, b_in, H1, MT, INTER,
                                               HID, nullptr, nullptr);
  wtrans<false><<<dim3(64, 256), dim3(32, 8), 0, stream>>>(w_out, WD, INTER,
                                                           HID, HID, 0);
  gemm128<2><<<dim3(16, 32), 256, 0, stream>>>(H1, WD, b_out, d_out, MT, HID,
                                               INTER, hidden, ATT);
}

// Round 14
// 748.497 us; speedup vs baseline: 1.0932x; 1.0932x over previous
//
#include <hip/hip_runtime.h>
#include <math.h>

#define HID 2048
#define NH 16
#define HD 128
#define INTER 8192
#define BB 2
#define SS 2048
#define MT (BB*SS)

typedef __bf16 bf16x8 __attribute__((ext_vector_type(8)));
typedef _Float16 f16x8 __attribute__((ext_vector_type(8)));
typedef float f32x4 __attribute__((ext_vector_type(4)));
typedef float f32x16 __attribute__((ext_vector_type(16)));
typedef unsigned short u16x8 __attribute__((ext_vector_type(8)));

__device__ __forceinline__ float bf2f(unsigned short u) {
  unsigned v = ((unsigned)u) << 16;
  return __builtin_bit_cast(float, v);
}
__device__ __forceinline__ unsigned short f2bf(float x) {
  unsigned u = __builtin_bit_cast(unsigned, x);
  u += 0x7fffu + ((u >> 16) & 1u);
  return (unsigned short)(u >> 16);
}
__device__ __forceinline__ unsigned short f2h(float x) {
  _Float16 h = (_Float16)x;  // v_cvt_f16_f32, RTN
  return __builtin_bit_cast(unsigned short, h);
}
__device__ __forceinline__ void gll16(const void* g, const void* lds) {
  __builtin_amdgcn_global_load_lds(
      (const __attribute__((address_space(1))) void*)g,
      (__attribute__((address_space(3))) void*)lds, 16, 0, 0);
}

// ---------------- fused LayerNorm: x1 f16 (for qkv gemm), x2 bf16 ----------
__global__ __launch_bounds__(256) void ln2k(
    const float* __restrict__ X, const float* __restrict__ s1,
    const float* __restrict__ b1, const float* __restrict__ s2,
    const float* __restrict__ b2, unsigned short* __restrict__ X1f,
    unsigned short* __restrict__ X2) {
  const int row = blockIdx.x;
  const int tid = threadIdx.x;
  const float* x = X + (long)row * HID;
  float4 v0 = ((const float4*)x)[tid * 2];
  float4 v1 = ((const float4*)x)[tid * 2 + 1];
  float s = v0.x + v0.y + v0.z + v0.w + v1.x + v1.y + v1.z + v1.w;
  float q = v0.x * v0.x + v0.y * v0.y + v0.z * v0.z + v0.w * v0.w +
            v1.x * v1.x + v1.y * v1.y + v1.z * v1.z + v1.w * v1.w;
#pragma unroll
  for (int off = 1; off < 64; off <<= 1) {
    s += __shfl_xor(s, off);
    q += __shfl_xor(q, off);
  }
  __shared__ float rs[4], rq[4];
  const int wid = tid >> 6, lane = tid & 63;
  if (lane == 0) { rs[wid] = s; rq[wid] = q; }
  __syncthreads();
  s = rs[0] + rs[1] + rs[2] + rs[3];
  q = rq[0] + rq[1] + rq[2] + rq[3];
  const float mu = s * (1.f / HID);
  const float var = q * (1.f / HID) - mu * mu;
  const float rstd = rsqrtf(var + 1e-5f);
  float xv[8] = {v0.x, v0.y, v0.z, v0.w, v1.x, v1.y, v1.z, v1.w};
  u16x8 o1, o2;
#pragma unroll
  for (int e = 0; e < 8; e++) {
    const int j = tid * 8 + e;
    const float xn = (xv[e] - mu) * rstd;
    o1[e] = f2h(xn * s1[j] + b1[j]);
    o2[e] = f2bf(xn * s2[j] + b2[j]);
  }
  *(u16x8*)(X1f + (long)row * HID + tid * 8) = o1;
  *(u16x8*)(X2 + (long)row * HID + tid * 8) = o2;
}

// -- weight transpose: W[k][ldn] cols [coff,coff+N) -> WT[N][K], bf16 or f16
template <bool F16>
__global__ __launch_bounds__(256) void wtrans(const float* __restrict__ W,
                                              unsigned short* __restrict__ WT,
                                              int K, int N, int ldn, int coff) {
  (void)N;
  __shared__ float t[32][33];
  const int n0 = blockIdx.x * 32, k0 = blockIdx.y * 32;
  const int tx = threadIdx.x, ty = threadIdx.y;
#pragma unroll
  for (int r = 0; r < 4; r++)
    t[ty + r * 8][tx] = W[(long)(k0 + ty + r * 8) * ldn + coff + n0 + tx];
  __syncthreads();
#pragma unroll
  for (int r = 0; r < 4; r++) {
    const float v = t[tx][ty + r * 8];
    WT[(long)(n0 + ty + r * 8) * K + k0 + tx] = F16 ? f2h(v) : f2bf(v);
  }
}

// ---------------- rope cos/sin table (f64 angle for accuracy) --------------
__global__ void rope_tab(float2* __restrict__ rope) {
  const int s = blockIdx.x, i = threadIdx.x;  // 2048 x 64
  const double ang = (double)s * pow(10000.0, -(double)i / 64.0);
  rope[s * 64 + i] = make_float2((float)cos(ang), (float)sin(ang));
}

// ---- f16 GEMM for all of qkv (128-tile, 32x32x16 MFMA) + fused RoPE -------
// C[4096][6144] = A[M][K](f16) @ Bt[N][K](f16)^T + bias.
// Per-wave 64x64 = 2x2 tiles of 32x32. C/D layout (m74/m101):
// col=lane&31, row=(reg&3)+8*(reg>>2)+4*(lane>>5).
__global__ __launch_bounds__(256) void gemmqkv(
    const unsigned short* __restrict__ A, const unsigned short* __restrict__ Bt,
    const float* __restrict__ bias, const float2* __restrict__ rope,
    unsigned short* __restrict__ QF, unsigned short* __restrict__ KF,
    unsigned short* __restrict__ Vb) {
  __shared__ unsigned short As[128 * 64];
  __shared__ unsigned short Bs[128 * 64];
  const int K = HID;
  const int tid = threadIdx.x;
  const int wid = tid >> 6, lane = tid & 63;
  const int l31 = lane & 31, lg = lane >> 5;
  const int wr = wid >> 1, wc = wid & 1;
  const long rA0 = (long)blockIdx.y * 128;
  const long rB0 = (long)blockIdx.x * 128;

  f32x16 acc[2][2] = {};

  for (int kt = 0; kt < K; kt += 64) {
#pragma unroll
    for (int i = 0; i < 4; i++) {
      const int lin = i * 4096 + wid * 1024 + (lane << 4);
      const int row = lin >> 7;
      const int cs = ((lin >> 4) & 7) ^ (row & 7);
      gll16(A + (rA0 + row) * (long)K + kt + cs * 8,
            (const char*)As + (i * 4096 + wid * 1024));
      gll16(Bt + (rB0 + row) * (long)K + kt + cs * 8,
            (const char*)Bs + (i * 4096 + wid * 1024));
    }
    __syncthreads();
#pragma unroll
    for (int kk = 0; kk < 4; kk++) {
      f16x8 av[2], bv[2];
#pragma unroll
      for (int t = 0; t < 2; t++) {
        const int rowA = wr * 64 + t * 32 + l31;
        const int cha = (kk * 2 + lg) ^ (rowA & 7);
        av[t] = *(const f16x8*)((const char*)As + rowA * 128 + cha * 16);
        const int rowB = wc * 64 + t * 32 + l31;
        const int chb = (kk * 2 + lg) ^ (rowB & 7);
        bv[t] = *(const f16x8*)((const char*)Bs + rowB * 128 + chb * 16);
      }
#pragma unroll
      for (int mt = 0; mt < 2; mt++)
#pragma unroll
        for (int nt = 0; nt < 2; nt++)
          acc[mt][nt] = __builtin_amdgcn_mfma_f32_32x32x16_f16(
              av[mt], bv[nt], acc[mt][nt], 0, 0, 0);
    }
    __syncthreads();
  }

  // epilogue: bias, RoPE pair rotation via shfl_xor(1) (col parity = lane
  // parity), f16 Q/K in [bh][s][128]; bf16 V in [m][2048].
  const int b_ = (int)(rA0 >> 11);
#pragma unroll
  for (int mt = 0; mt < 2; mt++) {
#pragma unroll
    for (int nt = 0; nt < 2; nt++) {
      const int col = (int)rB0 + wc * 64 + nt * 32 + l31;
      const float bsv = bias[col];
      const int cq = col & 2047;
      const int i = (cq & 127) >> 1;
      const int hh = (cq >> 7) & 15;
      const int d = cq & 127;
#pragma unroll
      for (int reg = 0; reg < 16; reg++) {
        const int row = (int)rA0 + wr * 64 + mt * 32 + (reg & 3) +
                        8 * (reg >> 2) + 4 * lg;
        const int srow = row & 2047;
        const float v = acc[mt][nt][reg] + bsv;
        if (col < 4096) {
          const float p = __shfl_xor(v, 1);
          const float2 cs = rope[srow * 64 + i];
          const float o = ((lane & 1) == 0) ? (v * cs.x - p * cs.y)
                                            : (p * cs.y + v * cs.x);
          unsigned short* dst = (col < 2048) ? QF : KF;
          dst[((long)(b_ * NH + hh) * SS + srow) * HD + d] = f2h(o);
        } else {
          Vb[(long)row * HID + (col - 4096)] = f2bf(v);
        }
      }
    }
  }
}

// ---------------- V transpose: Vbf [m][2048] -> VT [bh][128][s] ------------
__global__ __launch_bounds__(256) void vtrans(
    const unsigned short* __restrict__ Vb, unsigned short* __restrict__ VTb) {
  __shared__ unsigned short t[32][33];
  const int bh = blockIdx.z, b = bh >> 4, h = bh & 15;
  const int d0 = blockIdx.x * 32, s0 = blockIdx.y * 32;
  const int tx = threadIdx.x, ty = threadIdx.y;
#pragma unroll
  for (int r = 0; r < 4; r++) {
    const int s = s0 + ty + r * 8;
    t[ty + r * 8][tx] = Vb[((long)(b * SS + s)) * HID + h * HD + d0 + tx];
  }
  __syncthreads();
#pragma unroll
  for (int r = 0; r < 4; r++) {
    const int d = d0 + ty + r * 8;
    VTb[((long)bh * HD + d) * SS + s0 + tx] = t[tx][ty + r * 8];
  }
}

// --------- 128x128-tile bf16 GEMM, 32x32x16 MFMA inner loop ---------------
// MODE 0: bf16 out; 1: gelu+bf16; 2: +residF(f32)+residB(bf16), f32 out.
template <int MODE>
__global__ __launch_bounds__(256) void gemm128(
    const unsigned short* __restrict__ A, const unsigned short* __restrict__ Bt,
    const float* __restrict__ bias, void* __restrict__ Cout, int M, int N,
    int K, const float* __restrict__ residF,
    const unsigned short* __restrict__ residB) {
  (void)M;
  __shared__ unsigned short As[128 * 64];
  __shared__ unsigned short Bs[128 * 64];
  const int tid = threadIdx.x;
  const int wid = tid >> 6, lane = tid & 63;
  const int l31 = lane & 31, lg = lane >> 5;
  const int wr = wid >> 1, wc = wid & 1;
  const long rA0 = (long)blockIdx.y * 128;
  const long rB0 = (long)blockIdx.x * 128;

  f32x16 acc[2][2] = {};

  for (int kt = 0; kt < K; kt += 64) {
#pragma unroll
    for (int i = 0; i < 4; i++) {
      const int lin = i * 4096 + wid * 1024 + (lane << 4);
      const int row = lin >> 7;
      const int cs = ((lin >> 4) & 7) ^ (row & 7);
      gll16(A + (rA0 + row) * (long)K + kt + cs * 8,
            (const char*)As + (i * 4096 + wid * 1024));
      gll16(Bt + (rB0 + row) * (long)K + kt + cs * 8,
            (const char*)Bs + (i * 4096 + wid * 1024));
    }
    __syncthreads();
#pragma unroll
    for (int kk = 0; kk < 4; kk++) {
      bf16x8 av[2], bv[2];
#pragma unroll
      for (int t = 0; t < 2; t++) {
        const int rowA = wr * 64 + t * 32 + l31;
        const int cha = (kk * 2 + lg) ^ (rowA & 7);
        av[t] = *(const bf16x8*)((const char*)As + rowA * 128 + cha * 16);
        const int rowB = wc * 64 + t * 32 + l31;
        const int chb = (kk * 2 + lg) ^ (rowB & 7);
        bv[t] = *(const bf16x8*)((const char*)Bs + rowB * 128 + chb * 16);
      }
#pragma unroll
      for (int mt = 0; mt < 2; mt++)
#pragma unroll
        for (int nt = 0; nt < 2; nt++)
          acc[mt][nt] = __builtin_amdgcn_mfma_f32_32x32x16_bf16(
              av[mt], bv[nt], acc[mt][nt], 0, 0, 0);
    }
    __syncthreads();
  }

#pragma unroll
  for (int mt = 0; mt < 2; mt++) {
#pragma unroll
    for (int nt = 0; nt < 2; nt++) {
      const long col = rB0 + wc * 64 + nt * 32 + l31;
      const float bsv = bias[col];
#pragma unroll
      for (int reg = 0; reg < 16; reg++) {
        const long row = rA0 + wr * 64 + mt * 32 + (reg & 3) +
                         8 * (reg >> 2) + 4 * lg;
        float v = acc[mt][nt][reg] + bsv;
        if (MODE == 1) v = 0.5f * v * (1.f + erff(v * 0.7071067811865475f));
        if (MODE == 2) {
          v += residF[row * N + col] + bf2f(residB[row * N + col]);
          ((float*)Cout)[row * N + col] = v;
        } else {
          ((unsigned short*)Cout)[row * N + col] = f2bf(v);
        }
      }
    }
  }
}

// -- flash v5: 8 waves, KVBLK=64, dynamic big-first, dbuf + counted vmcnt ---
// QF/KF: [bh][s][128] f16; VT: [bh][128][s] bf16; AO: [b][s][h*128+d] bf16
__global__ __launch_bounds__(512, 2) void flash(
    const unsigned short* __restrict__ QF, const unsigned short* __restrict__ KF,
    const unsigned short* __restrict__ VT, const float* __restrict__ amask,
    unsigned short* __restrict__ AO) {
  __shared__ unsigned short Kt[2][64 * 128];  // 32KB [key][d] f16, dbuf
  __shared__ unsigned short Vt[2][128 * 64];  // 32KB [d][key] bf16, dbuf
  __shared__ unsigned short Pl[8 * 1024];     // 16KB per-wave 16x64 P bf16
  __shared__ float maskL[SS];                 //  8KB amask*log2e => 88KB total
  // big-first (LPT) dispatch: all qt=15 blocks first, then 14, ...
  const int z = blockIdx.x;
  const int qt = 15 - (z >> 5);
  const int bh = z & 31;
  const int b = bh >> 4, h = bh & 15;
  const int tid = threadIdx.x, wid = tid >> 6, lane = tid & 63;
  const int l16 = lane & 15, lhi = lane >> 4;
  const unsigned short* Qfb = QF + (long)bh * SS * HD;
  const unsigned short* Kfb = KF + (long)bh * SS * HD;
  const unsigned short* Vb = VT + (long)bh * HD * SS;
  const int q0 = qt * 128 + wid * 16;  // 16 q-rows per wave
  const float LOG2E = 1.4426950408889634f;
  const float SCL2 = 16.322232154552f;  // sqrt(128)*log2e

  {  // amask row -> LDS (prescaled); K-loop stays free of global loads
    float4 m0 = ((const float4*)(amask + (long)b * SS))[tid];
    m0.x *= LOG2E; m0.y *= LOG2E; m0.z *= LOG2E; m0.w *= LOG2E;
    ((float4*)maskL)[tid] = m0;
  }

  f16x8 qf[4];
#pragma unroll
  for (int ks = 0; ks < 4; ks++)
    qf[ks] = *(const f16x8*)(Qfb + (long)(q0 + l16) * HD + ks * 32 + lhi * 8);

  // stage tile kt2 (64 keys): 4 loads/thread x 512 thr = 32KB
  auto stage = [&](int kt2, int bu) {
#pragma unroll
    for (int i = 0; i < 2; i++) {
      const int lin = i * 8192 + wid * 1024 + (lane << 4);
      const int dst = i * 8192 + wid * 1024;
      {
        const int row = lin >> 8;  // K rows are 256B (128 f16)
        const int cs = ((lin >> 4) & 15) ^ (row & 7);
        gll16(Kfb + (long)(kt2 * 64 + row) * HD + cs * 8,
              (const char*)Kt[bu] + dst);
      }
      {
        const int row = lin >> 7;  // V rows are 128B (64 bf16 keys)
        const int cs = ((lin >> 4) & 7) ^ (row & 7);
        gll16(Vb + (long)row * SS + kt2 * 64 + cs * 8, (const char*)Vt[bu] + dst);
      }
    }
  };

  f32x4 accO[8] = {};
  float mrow[4], lrow[4];
#pragma unroll
  for (int r = 0; r < 4; r++) { mrow[r] = -3e38f; lrow[r] = 0.f; }

  const int nkt = 2 * qt + 2;
  stage(0, 0);
  asm volatile("s_waitcnt lgkmcnt(0)" ::: "memory");  // maskL writes done
  int buf = 0;
  for (int kt = 0; kt < nkt; kt++) {
    if (kt + 1 < nkt) {
      stage(kt + 1, buf ^ 1);  // 4 loads stay in flight across the barrier
      asm volatile("s_waitcnt vmcnt(4)" ::: "memory");  // tile kt landed
    } else {
      asm volatile("s_waitcnt vmcnt(0)" ::: "memory");
    }
    __builtin_amdgcn_s_barrier();  // raw barrier: no vmcnt(0) drain

    // wave-uniform causal skip (all this wave's rows above the key range)
    const bool active = (kt * 64 <= q0 + 15);
    if (active) {
      // S = Q K^T (f16, 16 MFMAs)
      f32x4 accS[4] = {};
      __builtin_amdgcn_s_setprio(1);
#pragma unroll
      for (int ks = 0; ks < 4; ks++) {
        f16x8 bk[4];
#pragma unroll
        for (int nf = 0; nf < 4; nf++) {
          const int row = nf * 16 + l16;
          const int ch = (ks * 4 + lhi) ^ (row & 7);
          bk[nf] = *(const f16x8*)((const char*)Kt[buf] + row * 256 + ch * 16);
        }
#pragma unroll
        for (int nf = 0; nf < 4; nf++)
          accS[nf] = __builtin_amdgcn_mfma_f32_16x16x32_f16(qf[ks], bk[nf],
                                                            accS[nf], 0, 0, 0);
      }
      __builtin_amdgcn_s_setprio(0);

      // scale to log2 domain + mask + causal
      float mk[4];
#pragma unroll
      for (int nf = 0; nf < 4; nf++) mk[nf] = maskL[kt * 64 + nf * 16 + l16];
#pragma unroll
      for (int nf = 0; nf < 4; nf++)
#pragma unroll
        for (int r = 0; r < 4; r++) {
          const int key = kt * 64 + nf * 16 + l16;
          const int qg = q0 + lhi * 4 + r;
          const float sv = accS[nf][r] * SCL2 + mk[nf];
          accS[nf][r] = (key > qg) ? -1e30f : sv;
        }

      // row maxes over the 16-lane group
      float mx[4];
#pragma unroll
      for (int r = 0; r < 4; r++) {
        float m0 = fmaxf(fmaxf(accS[0][r], accS[1][r]),
                         fmaxf(accS[2][r], accS[3][r]));
        m0 = fmaxf(m0, __shfl_xor(m0, 1));
        m0 = fmaxf(m0, __shfl_xor(m0, 2));
        m0 = fmaxf(m0, __shfl_xor(m0, 4));
        m0 = fmaxf(m0, __shfl_xor(m0, 8));
        mx[r] = m0;
      }
      // defer-rescale (THR=8 in log2 domain)
      bool defer = true;
#pragma unroll
      for (int r = 0; r < 4; r++) defer = defer && (mx[r] <= mrow[r] + 8.f);
      if (!__all(defer)) {
#pragma unroll
        for (int r = 0; r < 4; r++) {
          const float mnew = fmaxf(mrow[r], mx[r]);
          const float alpha = exp2f(mrow[r] - mnew);
          mrow[r] = mnew;
          lrow[r] *= alpha;
#pragma unroll
          for (int nf2 = 0; nf2 < 8; nf2++) accO[nf2][r] *= alpha;
        }
      }
      // P = exp2(S - m) -> per-wave LDS (16x64 bf16, 128B rows, swizzled)
#pragma unroll
      for (int r = 0; r < 4; r++) {
        const int rowl = lhi * 4 + r;
        const int qg = q0 + rowl;
        float rsum = 0.f;
#pragma unroll
        for (int nf = 0; nf < 4; nf++) {
          const int key = kt * 64 + nf * 16 + l16;
          const float p = (key > qg) ? 0.f : exp2f(accS[nf][r] - mrow[r]);
          rsum += p;
          const int colv = nf * 16 + l16;
          const int slot = (colv >> 3) ^ (rowl & 7);
          *(unsigned short*)((char*)Pl + wid * 2048 + rowl * 128 + slot * 16 +
                             (colv & 7) * 2) = f2bf(p);
        }
        rsum += __shfl_xor(rsum, 1);
        rsum += __shfl_xor(rsum, 2);
        rsum += __shfl_xor(rsum, 4);
        rsum += __shfl_xor(rsum, 8);
        lrow[r] += rsum;
      }

      // O += P V  (16 MFMAs, bf16)
      __builtin_amdgcn_s_setprio(1);
#pragma unroll
      for (int ks2 = 0; ks2 < 2; ks2++) {
        const int chp = (ks2 * 4 + lhi) ^ (l16 & 7);
        bf16x8 pa =
            *(const bf16x8*)((const char*)Pl + wid * 2048 + l16 * 128 + chp * 16);
#pragma unroll
        for (int nf2 = 0; nf2 < 8; nf2++) {
          const int rowv = nf2 * 16 + l16;
          const int ch = (ks2 * 4 + lhi) ^ (rowv & 7);
          bf16x8 vv =
              *(const bf16x8*)((const char*)Vt[buf] + rowv * 128 + ch * 16);
          accO[nf2] = __builtin_amdgcn_mfma_f32_16x16x32_bf16(pa, vv,
                                                              accO[nf2], 0, 0, 0);
        }
      }
      __builtin_amdgcn_s_setprio(0);
    }  // active
    __builtin_amdgcn_s_barrier();  // all waves done with buf before restage
    buf ^= 1;
  }

#pragma unroll
  for (int nf2 = 0; nf2 < 8; nf2++)
#pragma unroll
    for (int r = 0; r < 4; r++) {
      const int qg = q0 + lhi * 4 + r;
      const int d = nf2 * 16 + l16;
      const float v = accO[nf2][r] / lrow[r];
      AO[((long)(b * SS + qg)) * HID + h * HD + d] = f2bf(v);
    }
}

extern "C" void kernel_launch(void* const* d_in, const int* in_sizes, int n_in,
                              void* d_out, int out_size, void* d_ws,
                              size_t ws_size, hipStream_t stream) {
  (void)in_sizes; (void)n_in; (void)out_size;
  const float* hidden = (const float*)d_in[0];
  const float* amask = (const float*)d_in[1];
  const float* w_qkv = (const float*)d_in[2];
  const float* b_qkv = (const float*)d_in[3];
  const float* w_o = (const float*)d_in[4];
  const float* b_o = (const float*)d_in[5];
  const float* ln1s = (const float*)d_in[6];
  const float* ln1b = (const float*)d_in[7];
  const float* ln2s = (const float*)d_in[8];
  const float* ln2b = (const float*)d_in[9];
  const float* w_in = (const float*)d_in[10];
  const float* b_in = (const float*)d_in[11];
  const float* w_out = (const float*)d_in[12];
  const float* b_out = (const float*)d_in[13];

  char* ws = (char*)d_ws;
  // liveness-aliased workspace (<=178MB; >=209MB verified available)
  unsigned short* X1f = (unsigned short*)(ws + 0);           // 16MB f16, later AO
  unsigned short* X2  = (unsigned short*)(ws + 16777216);    // 16MB bf16
  unsigned short* Vbf = (unsigned short*)(ws + 33554432);    // 16MB bf16
  unsigned short* WQ  = (unsigned short*)(ws + 50331648);    // 24MB f16 [6144][2048]
  unsigned short* QFb = (unsigned short*)(ws + 75497472);    // 16MB f16
  unsigned short* KFb = (unsigned short*)(ws + 92274688);    // 16MB f16
  unsigned short* VTb = (unsigned short*)(ws + 109051904);   // 16MB bf16
  unsigned short* ATT = (unsigned short*)(ws + 125829120);   // 16MB bf16
  unsigned short* WD  = (unsigned short*)(ws + 142606336);   // 32MB bf16 (Wo/Win/Wout)
  float2* ROPE = (float2*)(ws + 176160768);                  // 1MB
  if (ws_size < 177209344) return;

  unsigned short* AO = X1f;  // x1 dead after gemmqkv
  unsigned short* H1 = WQ;   // WQ+QFb+KFb dead after flash: 64MB region

  ln2k<<<MT, 256, 0, stream>>>(hidden, ln1s, ln1b, ln2s, ln2b, X1f, X2);
  rope_tab<<<SS, 64, 0, stream>>>(ROPE);
  // qkv: one f16 GEMM (32x32 MFMA), rope fused for q,k
  wtrans<true><<<dim3(192, 64), dim3(32, 8), 0, stream>>>(w_qkv, WQ, HID,
                                                          3 * HID, 3 * HID, 0);
  gemmqkv<<<dim3(48, 32), 256, 0, stream>>>(X1f, WQ, b_qkv, ROPE, QFb, KFb,
                                            Vbf);
  vtrans<<<dim3(4, 64, 32), dim3(32, 8), 0, stream>>>(Vbf, VTb);
  flash<<<512, 512, 0, stream>>>(QFb, KFb, VTb, amask, AO);
  // attention projection
  wtrans<false><<<dim3(64, 64), dim3(32, 8), 0, stream>>>(w_o, WD, HID, HID,
                                                          HID, 0);
  gemm128<0><<<dim3(16, 32), 256, 0, stream>>>(AO, WD, b_o, ATT, MT, HID, HID,
                                               nullptr, nullptr);
  // mlp
  wtrans<false><<<dim3(256, 64), dim3(32, 8), 0, stream>>>(w_in, WD, HID,
                                                           INTER, INTER, 0);
  gemm128<1><<<dim3(64, 32), 256, 0, stream>>>(X2, WD, b_in, H1, MT, INTER,
                                               HID, nullptr, nullptr);
  wtrans<false><<<dim3(64, 256), dim3(32, 8), 0, stream>>>(w_out, WD, INTER,
                                                           HID, HID, 0);
  gemm128<2><<<dim3(16, 32), 256, 0, stream>>>(H1, WD, b_out, d_out, MT, HID,
                                               INTER, hidden, ATT);
}